// Round 2
// baseline (96.428 us; speedup 1.0000x reference)
//
#include <hip/hip_runtime.h>
#include <math.h>

// Problem constants (match reference)
#define NSEQ 64
#define TLEN 32768
#define G16_PER_SEQ 2048               // TLEN/16
#define NG16 (NSEQ * G16_PER_SEQ)      // 131072 level-16 groups
#define STEPS_PER_THREAD 4
#define NTHREADS (NG16 * 4)            // 524288 threads, 4 gyro steps each
#define BLOCK 256
#define NBLOCKS (NTHREADS / BLOCK)     // 2048
#define N0 5
#define DT 0.01f
#define HUBER_INV 200.0f               // 1/0.005

// W*HUBER^2 = 25.  mean denominators: 64*2043*3 and 64*1019*3; level-32 has extra 1/2.
__device__ __constant__ float C16 = 25.0f / (64.0f * 2043.0f * 3.0f);
__device__ __constant__ float C32 = 12.5f / (64.0f * 1019.0f * 3.0f);

__device__ __forceinline__ void mat_mul3(const float* A, const float* B, float* C) {
#pragma unroll
    for (int i = 0; i < 3; ++i) {
#pragma unroll
        for (int j = 0; j < 3; ++j) {
            C[3 * i + j] = A[3 * i + 0] * B[0 + j]
                         + A[3 * i + 1] * B[3 + j]
                         + A[3 * i + 2] * B[6 + j];
        }
    }
}

// Rodrigues: matches reference small-angle branches exactly
__device__ __forceinline__ void so3_exp_dev(float x, float y, float z, float* R) {
    float sq = x * x + y * y + z * z;
    float angle = sqrtf(fmaxf(sq, 1e-16f));
    bool small = sq < 1e-12f;
    float a = small ? 1.0f : angle;
    float sn, cs;
    __sincosf(a, &sn, &cs);
    float s = small ? (1.0f - sq * (1.0f / 6.0f)) : (sn / a);
    float c = small ? (0.5f - sq * (1.0f / 24.0f)) : ((1.0f - cs) / (a * a));
    float cxx = c * x * x, cyy = c * y * y, czz = c * z * z;
    float cxy = c * x * y, cxz = c * x * z, cyz = c * y * z;
    float sx = s * x, sy = s * y, sz = s * z;
    R[0] = 1.0f - cyy - czz; R[1] = cxy - sz;          R[2] = cxz + sy;
    R[3] = cxy + sz;         R[4] = 1.0f - cxx - czz;  R[5] = cyz - sx;
    R[6] = cxz - sy;         R[7] = cyz + sx;          R[8] = 1.0f - cxx - cyy;
}

// huber-sum over 3 components of log(Om^T * Xr) / HUBER
__device__ __forceinline__ float huber3_bmtm_log(const float* Om, const float* Xr) {
    float M[9];
#pragma unroll
    for (int j = 0; j < 3; ++j) {
#pragma unroll
        for (int k = 0; k < 3; ++k) {
            M[3 * j + k] = Om[0 + j] * Xr[0 + k]
                         + Om[3 + j] * Xr[3 + k]
                         + Om[6 + j] * Xr[6 + k];
        }
    }
    float tr = M[0] + M[4] + M[8];
    float cosv = 0.5f * (tr - 1.0f);
    cosv = fminf(fmaxf(cosv, -1.0f + 1e-7f), 1.0f - 1e-7f);
    float angle = acosf(cosv);
    float sn = sqrtf(fmaxf(1.0f - cosv * cosv, 0.0f));   // sin(acos(x)), angle in (0,pi)
    float sfac = angle / (2.0f * sn);
    float v0 = sfac * (M[7] - M[5]);
    float v1 = sfac * (M[2] - M[6]);
    float v2 = sfac * (M[3] - M[1]);
    float acc = 0.0f;
#pragma unroll
    for (int t = 0; t < 3; ++t) {
        float zz = (t == 0 ? v0 : (t == 1 ? v1 : v2)) * HUBER_INV;
        float az = fabsf(zz);
        acc += (az < 1.0f) ? 0.5f * zz * zz : az - 0.5f;
    }
    return acc;
}

// Ordered non-commutative butterfly combine: after this, every lane in a
// 2*mask-wide group holds the in-order product of the group's matrices.
// upper==true for the higher half (partner's matrix goes on the left).
__device__ __forceinline__ void ordered_combine(float* A, int mask, bool upper) {
    float L[9], R[9];
#pragma unroll
    for (int t = 0; t < 9; ++t) {
        float b = __shfl_xor(A[t], mask);
        L[t] = upper ? b : A[t];
        R[t] = upper ? A[t] : b;
    }
    float C[9];
    mat_mul3(L, R, C);
#pragma unroll
    for (int t = 0; t < 9; ++t) A[t] = C[t];
}

__global__ __launch_bounds__(256, 4) void gyro_loss_kernel(const float* __restrict__ xs,
                                                           const float* __restrict__ hat_xs,
                                                           float* __restrict__ partials) {
    __shared__ float lds[BLOCK * 12];   // 12 KB: 4 steps x 3 floats per thread
    const int tid = threadIdx.x;
    const int gt = blockIdx.x * BLOCK + tid;          // global thread id

    // ---- stage this block's hat_xs slice, fully coalesced float4 ----
    const float4* gp = reinterpret_cast<const float4*>(hat_xs) + (size_t)blockIdx.x * (BLOCK * 3);
    float4* lp = reinterpret_cast<float4*>(lds);
#pragma unroll
    for (int q = 0; q < 3; ++q) lp[q * BLOCK + tid] = gp[q * BLOCK + tid];
    __syncthreads();

    // ---- product of this thread's 4 per-step rotations (tree, depth 2) ----
    const float* h = &lds[12 * tid];
    float Ra[9], Rb[9], P[9], Q[9], Om[9];
    so3_exp_dev(DT * h[0], DT * h[1], DT * h[2], Ra);
    so3_exp_dev(DT * h[3], DT * h[4], DT * h[5], Rb);
    mat_mul3(Ra, Rb, P);
    so3_exp_dev(DT * h[6], DT * h[7], DT * h[8], Ra);
    so3_exp_dev(DT * h[9], DT * h[10], DT * h[11], Rb);
    mat_mul3(Ra, Rb, Q);
    mat_mul3(P, Q, Om);

    // ---- butterfly to the full 16-step product (4 lanes per group) ----
    ordered_combine(Om, 1, (tid & 1) != 0);
    ordered_combine(Om, 2, (tid & 2) != 0);
    // now all 4 lanes of the quad hold Om16 for group g:
    const int g = gt >> 2;

    // ---- xs_r: all quad lanes load the same float4 (same cacheline, L1 broadcast) ----
    float4 xv = *(reinterpret_cast<const float4*>(xs) + (size_t)g * 12);
    float Xr[9];
    so3_exp_dev(xv.x, xv.y, xv.z, Xr);

    float partial = 0.0f;
    if ((tid & 3) == 0 && (g & (G16_PER_SEQ - 1)) >= N0)
        partial = C16 * huber3_bmtm_log(Om, Xr);

    // ---- level 32: combine adjacent quads (xor 4) for both Om and Xr ----
    ordered_combine(Om, 4, (tid & 4) != 0);
    ordered_combine(Xr, 4, (tid & 4) != 0);
    if ((tid & 7) == 0 && ((g >> 1) & (G16_PER_SEQ / 2 - 1)) >= N0)
        partial += C32 * huber3_bmtm_log(Om, Xr);

    // ---- block reduction -> one partial per block ----
#pragma unroll
    for (int off = 32; off > 0; off >>= 1) partial += __shfl_down(partial, off);
    __shared__ float wsum[4];
    const int lane = tid & 63;
    const int wid = tid >> 6;
    if (lane == 0) wsum[wid] = partial;
    __syncthreads();
    if (tid == 0) partials[blockIdx.x] = wsum[0] + wsum[1] + wsum[2] + wsum[3];
}

__global__ __launch_bounds__(256) void finish_kernel(const float* __restrict__ partials,
                                                     float* __restrict__ out) {
    const int tid = threadIdx.x;
    float s = 0.0f;
#pragma unroll
    for (int q = 0; q < NBLOCKS / 256; ++q) s += partials[q * 256 + tid];
#pragma unroll
    for (int off = 32; off > 0; off >>= 1) s += __shfl_down(s, off);
    __shared__ float wsum[4];
    if ((tid & 63) == 0) wsum[tid >> 6] = s;
    __syncthreads();
    if (tid == 0) out[0] = wsum[0] + wsum[1] + wsum[2] + wsum[3];
}

extern "C" void kernel_launch(void* const* d_in, const int* in_sizes, int n_in,
                              void* d_out, int out_size, void* d_ws, size_t ws_size,
                              hipStream_t stream) {
    const float* xs     = (const float*)d_in[0];
    // d_in[1] = dp, unused by the forward pass
    const float* hat_xs = (const float*)d_in[2];
    float* out = (float*)d_out;
    float* partials = (float*)d_ws;     // NBLOCKS floats, written before read

    gyro_loss_kernel<<<NBLOCKS, BLOCK, 0, stream>>>(xs, hat_xs, partials);
    finish_kernel<<<1, 256, 0, stream>>>(partials, out);
}